// Round 8
// baseline (59.220 us; speedup 1.0000x reference)
//
#include <hip/hip_runtime.h>

#define BB 32
#define CC 1024
#define QQ 128
#define EE 512

typedef unsigned int uint32;
typedef unsigned short u16;
typedef __bf16 bf16x8 __attribute__((ext_vector_type(8)));
typedef float f32x4 __attribute__((ext_vector_type(4)));

// workspace layout (bytes)
#define QMF_OFF  (0u)                  // bf16 frag-major: [b][ks 0..15][nf 0..7][lane][8]  (qm' = q*ws_m + ws_c)
#define QTF_OFF  (4u<<20)              // bf16 frag-major: [b][ks2 0..3][ne 0..31][lane][8]
#define PV_OFF   (8u<<20)              // f32 [b][64 groups][512]
#define QDP_OFF  (12u<<20)             // f32 [b][et 0..3][128] qdot partials
#define MT_OFF   ((12u<<20) + 65536u)  // f32 [b][64]
#define ST_OFF   (MT_OFF + 8192u)      // f32 [b][64]

__device__ __forceinline__ u16 bfc(float f){
  __bf16 h = (__bf16)f;                // HW v_cvt (RNE)
  return __builtin_bit_cast(u16, h);
}
__device__ __forceinline__ float bf2f(uint32 lo16){
  return __builtin_bit_cast(float, lo16 << 16);
}

// ---- fused prep: per (b, e-slice et): qm' frags + qt frags + qdot partial ----
__global__ __launch_bounds__(256) void k_prep(const float* __restrict__ q,
                                              const float* __restrict__ ws,
                                              unsigned char* __restrict__ wsp){
  const int b = blockIdx.x >> 2, et = blockIdx.x & 3, e0 = et*128;
  __shared__ u16 tm[128*136];          // qm' = q*ws_m + ws_c (bf16)
  __shared__ u16 tt[128*136];          // raw q (bf16)
  const int tid = threadIdx.x;
  float* qdp = (float*)(wsp + QDP_OFF) + (size_t)(b*4 + et)*128;
  #pragma unroll
  for (int i=0;i<16;i++){
    int id = tid + i*256;
    int qi = id >> 5;
    int el = (id & 31) << 2;
    float4 v = *(const float4*)(q + (size_t)(b*QQ+qi)*EE + e0 + el);
    float4 a = *(const float4*)(ws +          e0 + el);
    float4 c = *(const float4*)(ws +   EE +   e0 + el);
    float4 m = *(const float4*)(ws + 2*EE +   e0 + el);
    ushort4 um; um.x = bfc(v.x*m.x + c.x); um.y = bfc(v.y*m.y + c.y);
                um.z = bfc(v.z*m.z + c.z); um.w = bfc(v.w*m.w + c.w);
    *(ushort4*)&tm[qi*136 + el] = um;
    ushort4 ut; ut.x = bfc(v.x); ut.y = bfc(v.y); ut.z = bfc(v.z); ut.w = bfc(v.w);
    *(ushort4*)&tt[qi*136 + el] = ut;
    // qdot partial over this 128-e slice: 32 consecutive threads share one qi
    float d = v.x*a.x + v.y*a.y + v.z*a.z + v.w*a.w;
    d += __shfl_xor(d,1); d += __shfl_xor(d,2); d += __shfl_xor(d,4);
    d += __shfl_xor(d,8); d += __shfl_xor(d,16);
    if ((tid & 31) == 0) qdp[qi] = d;
  }
  __syncthreads();
  const int lane = tid & 63, wv = tid >> 6, l15 = lane & 15, l4 = lane >> 4;
  uint4* qmf = (uint4*)(wsp + QMF_OFF);
  uint4* qtf = (uint4*)(wsp + QTF_OFF);
  #pragma unroll
  for (int i=0;i<8;i++){
    int f = wv*8 + i;
    int kl = f >> 3, nf = f & 7;
    uint4 u = *(const uint4*)&tm[(nf*16 + l15)*136 + kl*32 + l4*8];
    qmf[(size_t)((b*16 + et*4 + kl)*8 + nf)*64 + lane] = u;
  }
  #pragma unroll
  for (int i=0;i<8;i++){
    int f = wv*8 + i;
    int ks2 = f >> 3, nl = f & 7, ne = et*8 + nl;
    uint32 x[4];
    #pragma unroll
    for (int p=0;p<4;p++){
      u16 t0 = tt[(ks2*32 + l4*8 + 2*p    )*136 + nl*16 + l15];
      u16 t1 = tt[(ks2*32 + l4*8 + 2*p + 1)*136 + nl*16 + l15];
      x[p] = (uint32)t0 | ((uint32)t1 << 16);
    }
    uint4 u; u.x = x[0]; u.y = x[1]; u.z = x[2]; u.w = x[3];
    qtf[(size_t)((b*4 + ks2)*32 + ne)*64 + lane] = u;
  }
}

// ---- main: 256 persistent blocks (1/CU) x 8 waves; block = TWO 64-row tiles of one batch.
// Pipeline: read(t1) overlaps GEMM1(t0); qm frags/qd loaded once; GEMM2 does both
// tiles per qtf-DMA pass (one DMA, 16 MFMA, 32 stores) -> one long write phase.
__global__ __attribute__((amdgpu_flat_work_group_size(512, 512)))
           __attribute__((amdgpu_waves_per_eu(2)))
void k_main(const float* __restrict__ ctx,
            unsigned char* __restrict__ wsp,
            float* __restrict__ out){
  __shared__ __align__(16) unsigned char buf[2][65536]; // ctx bf16 [64][512] swz; buf[i][0:16K)=pfrag_i; buf[0][16K:48K)=qstage
  __shared__ __align__(16) float mxA[2][64*8];
  __shared__ __align__(16) float smA[2][64*8];
  __shared__ float wrowA[2][4][16];

  const int bid = blockIdx.x;
  const int sw  = (bid & 7)*32 + (bid >> 3);   // XCD-contiguous (256%8==0): 4 batches/XCD
  const int b   = sw >> 3;
  const int pr  = sw & 7;
  const int t0  = pr*2, t1 = pr*2 + 1;
  const int tid = threadIdx.x;
  const int lane = tid & 63;
  const int w    = tid >> 6;                   // q-slice (GEMM1) / (rg,eh) (GEMM2)
  const int l15  = lane & 15;
  const int l4   = lane >> 4;
  const int rg   = w >> 1;
  const int eh   = w & 1;

  // ---- issue t0 ctx loads ----
  const float4* cb0 = (const float4*)(ctx + (size_t)(b*CC + t0*64)*EE);
  const float4* cb1 = (const float4*)(ctx + (size_t)(b*CC + t1*64)*EE);
  float4 v[16];
  #pragma unroll
  for (int i=0;i<16;i++) v[i] = cb0[i*512 + tid];

  // qm' A-frags (once per block) + qdot (sum of 4 e-slice partials)
  const uint4* qmf4 = (const uint4*)(wsp + QMF_OFF);
  bf16x8 a[16];
  #pragma unroll
  for (int ks=0; ks<16; ks++)
    a[ks] = __builtin_bit_cast(bf16x8, qmf4[(size_t)((b*16 + ks)*8 + w)*64 + lane]);
  float qdv[4];
  {
    const float* qdp = (const float*)(wsp + QDP_OFF) + (size_t)b*512;
    #pragma unroll
    for (int r=0;r<4;r++){
      const int qi = w*16 + l4*4 + r;
      qdv[r] = qdp[qi] + qdp[128+qi] + qdp[256+qi] + qdp[384+qi];
    }
  }

  const int colb = (tid & 127)*8;
  auto stage_write = [&](unsigned char* dst){
    #pragma unroll
    for (int i=0;i<16;i++){
      int row = i*4 + (tid >> 7);
      uint2 u;
      u.x = (uint32)bfc(v[i].x) | ((uint32)bfc(v[i].y) << 16);
      u.y = (uint32)bfc(v[i].z) | ((uint32)bfc(v[i].w) << 16);
      *(uint2*)(dst + row*1024 + (colb ^ ((row & 7) << 4))) = u;
    }
  };

  stage_write(buf[0]);
  __syncthreads();                             // b0: buf0 ready

  // ---- issue t1 ctx loads (complete during GEMM1(t0) at HBM pace) ----
  #pragma unroll
  for (int i=0;i<16;i++) v[i] = cb1[i*512 + tid];

  // ---- GEMM1(t0): flipped, A=regs, B=buf0 LDS ----
  auto gemm1 = [&](const unsigned char* bp, f32x4* acc){
    #pragma unroll
    for (int cc=0;cc<4;cc++) acc[cc] = (f32x4){0.f,0.f,0.f,0.f};
    #pragma unroll
    for (int ks=0; ks<16; ks++){
      #pragma unroll
      for (int cc=0; cc<4; cc++){
        const int row = cc*16 + l15;
        bf16x8 bf = __builtin_bit_cast(bf16x8,
          *(const uint4*)(bp + row*1024 + ((ks*64 + l4*16) ^ ((row & 7) << 4))));
        acc[cc] = __builtin_amdgcn_mfma_f32_16x16x32_bf16(a[ks], bf, acc[cc], 0, 0, 0);
      }
    }
  };
  f32x4 acc[4];
  gemm1(buf[0], acc);
  __syncthreads();                             // b1: buf0 reads done

  // ---- softmax (m=0 exp, shift-invariant; clamp 80) -> pfrag + stats ----
  auto softmax = [&](int ti, f32x4* ac){
    #pragma unroll
    for (int cc=0; cc<4; cc++){
      float m = -3.0e38f, s = 0.f;
      u16 hb[4];
      #pragma unroll
      for (int r=0;r<4;r++){
        float vv = ac[cc][r] + qdv[r];
        vv = fminf(vv, 80.f);
        m = fmaxf(m, vv);
        u16 h = bfc(__expf(vv));
        hb[r] = h;
        s += bf2f(h);
      }
      uint2 u; u.x = (uint32)hb[0] | ((uint32)hb[1]<<16);
               u.y = (uint32)hb[2] | ((uint32)hb[3]<<16);
      *(uint2*)(buf[ti] + (cc*4 + (w>>1))*1024 + (((w&1)*2 + (l4>>1))*16 + l15)*16 + (l4&1)*8) = u;
      m = fmaxf(m, __shfl_xor(m, 16)); m = fmaxf(m, __shfl_xor(m, 32));
      s += __shfl_xor(s, 16);          s += __shfl_xor(s, 32);
      if (l4 == 0){
        mxA[ti][(cc*16 + l15)*8 + w] = m;
        smA[ti][(cc*16 + l15)*8 + w] = s;
      }
    }
  };
  softmax(0, acc);
  stage_write(buf[1]);
  __syncthreads();                             // b2: buf1 + pfrag0 + stats0 ready

  // t0 stats consumers + pa0 + dma(0); then GEMM1(t1)
  auto rden_of = [&](int ti, float* rd){
    #pragma unroll
    for (int r=0;r<4;r++){
      const int c = rg*16 + l4*4 + r;
      f32x4 s0 = *(const f32x4*)&smA[ti][c*8];
      f32x4 s1 = *(const f32x4*)&smA[ti][c*8 + 4];
      rd[r] = 1.f/(s0[0]+s0[1]+s0[2]+s0[3]+s1[0]+s1[1]+s1[2]+s1[3]);
    }
  };
  auto q2c_stats = [&](int ti, int tglob){
    if (eh != 0) return;
    float mf[4];
    #pragma unroll
    for (int r=0;r<4;r++){
      const int c = rg*16 + l4*4 + r;
      f32x4 m0 = *(const f32x4*)&mxA[ti][c*8];
      f32x4 m1 = *(const f32x4*)&mxA[ti][c*8 + 4];
      mf[r] = fmaxf(fmaxf(fmaxf(m0[0],m0[1]), fmaxf(m0[2],m0[3])),
                    fmaxf(fmaxf(m1[0],m1[1]), fmaxf(m1[2],m1[3])));
    }
    float m16 = fmaxf(fmaxf(mf[0],mf[1]), fmaxf(mf[2],mf[3]));
    m16 = fmaxf(m16, __shfl_xor(m16, 16));
    m16 = fmaxf(m16, __shfl_xor(m16, 32));
    float wr[4], s16 = 0.f;
    #pragma unroll
    for (int r=0;r<4;r++){ wr[r] = __expf(mf[r] - m16); s16 += wr[r]; }
    s16 += __shfl_xor(s16, 16);
    s16 += __shfl_xor(s16, 32);
    if (l15 == 0){
      #pragma unroll
      for (int r=0;r<4;r++) wrowA[ti][rg][l4*4 + r] = wr[r];
    }
    if (lane == 0){
      ((float*)(wsp + MT_OFF))[b*64 + tglob*4 + rg] = m16;
      ((float*)(wsp + ST_OFF))[b*64 + tglob*4 + rg] = s16;
    }
  };

  float rden0[4], rden1[4];
  rden_of(0, rden0);
  q2c_stats(0, t0);
  bf16x8 pa0[4], pa1[4];
  #pragma unroll
  for (int k2=0;k2<4;k2++)
    pa0[k2] = __builtin_bit_cast(bf16x8, *(const uint4*)(buf[0] + (rg*4 + k2)*1024 + lane*16));

  // qtf DMA: 8 e-eighth passes, dbuf 2x16KB in buf0[16K:48K) (ctx dead)
  unsigned char* qstage = buf[0] + 16384;
  const unsigned char* qtfb = wsp + QTF_OFF + (size_t)b*131072;
  auto dma = [&](int p){
    #pragma unroll
    for (int j=0;j<2;j++){
      const int f = w*2 + j;
      const int ks2 = f >> 2, nl = f & 3;
      const unsigned char* g = qtfb + (size_t)(ks2*32 + p*4 + nl)*1024 + lane*16;
      __builtin_amdgcn_global_load_lds(
        (const __attribute__((address_space(1))) uint32*)g,
        (__attribute__((address_space(3))) uint32*)(qstage + (p&1)*16384 + f*1024),
        16, 0, 0);
    }
  };
  dma(0);

  gemm1(buf[1], acc);
  __syncthreads();                             // b3: buf1 reads done; dma(0) landed
  softmax(1, acc);
  __syncthreads();                             // b4: pfrag1 + stats1 ready
  rden_of(1, rden1);
  q2c_stats(1, t1);
  #pragma unroll
  for (int k2=0;k2<4;k2++)
    pa1[k2] = __builtin_bit_cast(bf16x8, *(const uint4*)(buf[1] + (rg*4 + k2)*1024 + lane*16));

  // ---- GEMM2: both tiles per pass; rows rg*16..+15, e = p*64 + eh*32 + 0..31 ----
  float* ob0 = out + (size_t)(b*CC + t0*64 + rg*16)*EE;
  float* ob1 = out + (size_t)(b*CC + t1*64 + rg*16)*EE;
  #pragma unroll
  for (int p=0; p<8; p++){
    if (p < 7) dma(p+1);
    const unsigned char* qs = qstage + (p&1)*16384;
    f32x4 A0 = (f32x4){0.f,0.f,0.f,0.f};
    f32x4 A1 = (f32x4){0.f,0.f,0.f,0.f};
    f32x4 B0 = (f32x4){0.f,0.f,0.f,0.f};
    f32x4 B1 = (f32x4){0.f,0.f,0.f,0.f};
    #pragma unroll
    for (int k2=0;k2<4;k2++){
      bf16x8 b0 = __builtin_bit_cast(bf16x8, *(const uint4*)(qs + (k2*4 + eh*2 + 0)*1024 + lane*16));
      bf16x8 b1 = __builtin_bit_cast(bf16x8, *(const uint4*)(qs + (k2*4 + eh*2 + 1)*1024 + lane*16));
      A0 = __builtin_amdgcn_mfma_f32_16x16x32_bf16(pa0[k2], b0, A0, 0, 0, 0);
      A1 = __builtin_amdgcn_mfma_f32_16x16x32_bf16(pa0[k2], b1, A1, 0, 0, 0);
      B0 = __builtin_amdgcn_mfma_f32_16x16x32_bf16(pa1[k2], b0, B0, 0, 0, 0);
      B1 = __builtin_amdgcn_mfma_f32_16x16x32_bf16(pa1[k2], b1, B1, 0, 0, 0);
    }
    #pragma unroll
    for (int r=0;r<4;r++){
      const size_t ro = (size_t)(l4*4 + r)*EE + p*64 + eh*32;
      ob0[ro +      l15] = A0[r]*rden0[r];
      ob0[ro + 16 + l15] = A1[r]*rden0[r];
      ob1[ro +      l15] = B0[r]*rden1[r];
      ob1[ro + 16 + l15] = B1[r]*rden1[r];
    }
    __syncthreads();                           // dma(p+1) landed; qstage flip safe
  }

  // ---- fused q2c partials: both tiles, rows rg*16..+15 x e-half eh (L3-hot) ----
  #pragma unroll
  for (int ti=0; ti<2; ti++){
    const int tg = ti ? t1 : t0;
    const float4* cq = (const float4*)(ctx + (size_t)(b*CC + tg*64 + rg*16)*EE + eh*256) + lane;
    float4 a4; a4.x = 0.f; a4.y = 0.f; a4.z = 0.f; a4.w = 0.f;
    #pragma unroll
    for (int rr=0; rr<16; rr++){
      float wv = wrowA[ti][rg][rr];
      float4 g = cq[(size_t)rr*128];
      a4.x = fmaf(wv, g.x, a4.x); a4.y = fmaf(wv, g.y, a4.y);
      a4.z = fmaf(wv, g.z, a4.z); a4.w = fmaf(wv, g.w, a4.w);
    }
    float* pv = (float*)(wsp + PV_OFF) + (size_t)(b*64 + tg*4 + rg)*EE + eh*256 + lane*4;
    *(float4*)pv = a4;
  }
}

// ---- q2c combine: 64 group-partials per batch ----
__global__ __launch_bounds__(256) void k_fin(unsigned char* __restrict__ wsp,
                                             float* __restrict__ out){
  const int b = blockIdx.x;
  __shared__ float sc_s[64];
  const int tid = threadIdx.x;
  if (tid < 64){
    float Mg = ((const float*)(wsp + MT_OFF))[b*64 + tid];
    float Sg = ((const float*)(wsp + ST_OFF))[b*64 + tid];
    float M = Mg;
    #pragma unroll
    for (int off=1; off<64; off<<=1) M = fmaxf(M, __shfl_xor(M, off));
    float ev = __expf(Mg - M);
    float ds = ev * Sg;
    #pragma unroll
    for (int off=1; off<64; off<<=1) ds += __shfl_xor(ds, off);
    sc_s[tid] = ev / ds;
  }
  __syncthreads();
  const float* pv = (const float*)(wsp + PV_OFF) + (size_t)b*64*EE;
  float a0 = 0.f, a1 = 0.f;
  #pragma unroll 8
  for (int g=0; g<64; g++){
    float s = sc_s[g];
    a0 = fmaf(s, pv[g*EE + tid],       a0);
    a1 = fmaf(s, pv[g*EE + tid + 256], a1);
  }
  size_t base = (size_t)BB*CC*EE + (size_t)b*EE;
  out[base + tid]       = a0;
  out[base + tid + 256] = a1;
}

extern "C" void kernel_launch(void* const* d_in, const int* in_sizes, int n_in,
                              void* d_out, int out_size, void* d_ws, size_t ws_size,
                              hipStream_t stream){
  const float* ctx = (const float*)d_in[0];
  const float* q   = (const float*)d_in[1];
  const float* ws  = (const float*)d_in[2];
  float* out = (float*)d_out;
  unsigned char* wsp = (unsigned char*)d_ws;

  k_prep<<<dim3(BB*4), dim3(256), 0, stream>>>(q, ws, wsp);
  k_main<<<dim3(256),  dim3(512), 0, stream>>>(ctx, wsp, out);
  k_fin <<<dim3(BB),   dim3(256), 0, stream>>>(wsp, out);
}